// Round 21
// baseline (632.382 us; speedup 1.0000x reference)
//
#include <hip/hip_runtime.h>

typedef __attribute__((ext_vector_type(8))) short short8;
typedef __attribute__((ext_vector_type(4))) float f32x4;
typedef __attribute__((ext_vector_type(4))) unsigned short u16x4;
typedef unsigned short u16;
typedef unsigned int u32;

#define DEV static __device__ __forceinline__

DEV u16 f2b(float f) {
  u32 u = __builtin_bit_cast(u32, f);
  return (u16)((u + 0x7fffu + ((u >> 16) & 1u)) >> 16);
}
DEV float b2f(u16 h) {
  u32 u = ((u32)h) << 16;
  return __builtin_bit_cast(float, u);
}
DEV short8 ld8(const u16* p) { return *reinterpret_cast<const short8*>(p); }
DEV f32x4 mfma16(short8 a, short8 b, f32x4 c) {
  return __builtin_amdgcn_mfma_f32_16x16x32_bf16(a, b, c, 0, 0, 0);
}
DEV float wredsum(float v) {
#pragma unroll
  for (int off = 1; off < 64; off <<= 1) v += __shfl_xor(v, off);
  return v;
}

#define GLL(gp, lp) __builtin_amdgcn_global_load_lds( \
    (const __attribute__((address_space(1))) void*)(gp), \
    (__attribute__((address_space(3))) void*)(lp), 16, 0, 0)

// ---- weight arena (u16 element offsets) ----
#define WQKV   0         // [768][256]  (pre-scaled by gamma1)
#define WPROJ  196608    // [256][256]
#define WM1    262144    // [1024][256] (pre-scaled by gamma2)
#define WM2    524288    // [256][1024]
#define WSKIP  786432    // [256][256]
#define WUP    851968    // [4][256][512]  kk = kh*2+kw

// ---- ws byte offsets ----
#define OFF_BIAS 2752512u
#define OFF_SC   2883584u     // bf16 sc: conv shortcut -> x2 [73728][256]
#define OFF_OVR  40632320u    // overlay:
// phase A: xt @OVR (18,874,368)  [dead after k1g]
// phase B: skt @OVR (37,748,736) [dead after k2y]
// persistent: stat @+52,000,000; pstat @+52,600,000; sgb @+55,000,000
#define OFF_STAT (OFF_OVR + 52000000u)
#define OFF_PST  (OFF_OVR + 52600000u)
#define OFF_SGB  (OFF_OVR + 55000000u)
// d_out scratch: ybuf u16 @0 (37,748,736); obr u16 @37,748,736 (37,748,736)
#define WS_NEED  96227328u

__global__ void k_sentinel(float* out) { out[threadIdx.x] = 31337.0f; }

// ================= prep: weights -> bf16, bias table =========================
__global__ __launch_bounds__(256) void k_prep(
    const float* qkv_w, const float* proj_w, const float* mlp_w1,
    const float* mlp_w2, const float* skip_w, const float* up_w,
    const float* rpb, const float* g1, const float* g2, u16* W, float* bias_g) {
  int i = blockIdx.x * 256 + threadIdx.x;
  if (i < 196608) { W[WQKV + i] = f2b(qkv_w[i] * g1[i & 255]); return; }
  i -= 196608;
  if (i < 65536) { W[WPROJ + i] = f2b(proj_w[i]); return; }
  i -= 65536;
  if (i < 262144) { W[WM1 + i] = f2b(mlp_w1[i] * g2[i & 255]); return; }
  i -= 262144;
  if (i < 262144) { W[WM2 + i] = f2b(mlp_w2[i]); return; }
  i -= 262144;
  if (i < 65536) { W[WSKIP + i] = f2b(skip_w[i]); return; }
  i -= 65536;
  if (i < 524288) {
    int ci = i & 511; int rest = i >> 9; int co = rest & 255; int kk = rest >> 8;
    W[WUP + i] = f2b(up_w[ci * 1024 + co * 4 + kk]);
    return;
  }
  i -= 524288;
  if (i < 32768) {
    int h = i >> 12, r = i & 4095, ii = r >> 6, j = r & 63;
    float v;
    if (j >= 49) v = -1e30f;
    else if (ii >= 49) v = 0.f;
    else {
      int d0 = (ii / 7 - j / 7) + 6, d1 = (ii % 7 - j % 7) + 6;
      v = rpb[(d0 * 13 + d1) * 8 + h];
    }
    bias_g[i] = v;
  }
}

// ====== K_FOLD: wave-parallel fold dot-products (Sg2, Sb2, Sb1) ===============
__global__ __launch_bounds__(256) void k_fold(
    const float* mlp_w1, const float* qkv_w, const float* g1, const float* be1,
    const float* g2, const float* be2, float* sgb) {
  int wave = threadIdx.x >> 6, lane = threadIdx.x & 63;
  int id = blockIdx.x * 4 + wave;
  const float* wsrc;
  const float* vec;
  int out;
  if (id < 1024) { wsrc = mlp_w1 + (size_t)id * 256; vec = g2; out = id; }
  else if (id < 2048) { wsrc = mlp_w1 + (size_t)(id - 1024) * 256; vec = be2; out = id; }
  else { wsrc = qkv_w + (size_t)(id - 2048) * 256; vec = be1; out = 2816 + (id - 2048); }
  float s = 0.f;
#pragma unroll
  for (int j = 0; j < 4; j++) {
    int k = j * 64 + lane;
    s += vec[k] * wsrc[k];
  }
  s = wredsum(s);
  if (lane == 0) sgb[out] = s;
}

// ============== NCHW f32 -> NHWC bf16 tiled transpose (for x) =================
__global__ __launch_bounds__(256) void k_tr(const float* src, u16* dst, int C, int HW) {
  __shared__ float t[32][33];
  int hw0 = blockIdx.x * 32, c0 = blockIdx.y * 32, b = blockIdx.z;
  int tx = threadIdx.x & 31, ty = threadIdx.x >> 5;
  const float* s = src + (size_t)b * C * HW;
  u16* d = dst + (size_t)b * C * HW;
#pragma unroll
  for (int i = 0; i < 4; i++)
    t[ty + i * 8][tx] = s[(size_t)(c0 + ty + i * 8) * HW + hw0 + tx];
  __syncthreads();
#pragma unroll
  for (int i = 0; i < 4; i++)
    d[(size_t)(hw0 + ty + i * 8) * C + c0 + tx] = f2b(t[tx][ty + i * 8]);
}

// ===== batched skip transpose: skip[b][c][h][w] -> skt[b][h][w][c] (bf16) =====
__global__ __launch_bounds__(256) void k_tr_skip(const float* src, u16* dst) {
  __shared__ float t[32][33];
  int w0 = blockIdx.x * 32, c0 = blockIdx.y * 32;
  int z = blockIdx.z;
  int b = z / 96, h = z - b * 96;
  int tx = threadIdx.x & 31, ty = threadIdx.x >> 5;
  const float* s = src + (size_t)b * 256 * 9216 + (size_t)h * 96;
  u16* d = dst + (((size_t)b * 96 + h) * 96) * 256;
#pragma unroll
  for (int i = 0; i < 4; i++)
    t[ty + i * 8][tx] = s[(size_t)(c0 + ty + i * 8) * 9216 + w0 + tx];
  __syncthreads();
#pragma unroll
  for (int i = 0; i < 4; i++)
    d[(size_t)(w0 + ty + i * 8) * 256 + c0 + tx] = f2b(t[tx][ty + i * 8]);
}

// ====== K1G: convT as GEMM (M=18432,N=256,K=512) x4 parities, dbuf gll ========
__global__ __launch_bounds__(256) void k1g(
    const u16* W, const u16* xt, const float* up_b, u16* sc) {
  __shared__ __align__(16) u16 Ab[2][4096];
  __shared__ __align__(16) u16 Bb[2][4096];
  int tid = threadIdx.x;
  int lane = tid & 63, wave = tid >> 6;
  int m = lane & 15, gq = lane >> 4;
  int wr = wave >> 1, wc = wave & 1;
  int bm = blockIdx.x * 128, bn = blockIdx.y * 128;
  int kk = blockIdx.z, kh = kk >> 1, kw = kk & 1;
  const u16* Ag = xt + (size_t)bm * 512;
  const u16* Bg = W + WUP + (size_t)kk * 131072 + (size_t)bn * 512;
  f32x4 acc[4][4] = {};
#pragma unroll
  for (int c = 0; c < 2; c++) {
    int flat = (wave * 2 + c) * 512 + lane * 8;
    int r = flat >> 5, cc = flat & 31;
    GLL(Ag + (size_t)r * 512 + cc, &Ab[0][(wave * 2 + c) * 512]);
    GLL(Bg + (size_t)r * 512 + cc, &Bb[0][(wave * 2 + c) * 512]);
  }
  __syncthreads();
  int cur = 0;
  for (int ki = 0; ki < 16; ki++) {
    if (ki < 15) {
      int kkk = (ki + 1) * 32;
#pragma unroll
      for (int c = 0; c < 2; c++) {
        int flat = (wave * 2 + c) * 512 + lane * 8;
        int r = flat >> 5, cc = flat & 31;
        GLL(Ag + (size_t)r * 512 + kkk + cc, &Ab[cur ^ 1][(wave * 2 + c) * 512]);
        GLL(Bg + (size_t)r * 512 + kkk + cc, &Bb[cur ^ 1][(wave * 2 + c) * 512]);
      }
    }
    short8 aF[4], bF[4];
#pragma unroll
    for (int mt = 0; mt < 4; mt++)
      aF[mt] = ld8(&Ab[cur][(wr * 64 + mt * 16 + m) * 32 + gq * 8]);
#pragma unroll
    for (int nt = 0; nt < 4; nt++)
      bF[nt] = ld8(&Bb[cur][(wc * 64 + nt * 16 + m) * 32 + gq * 8]);
#pragma unroll
    for (int mt = 0; mt < 4; mt++)
#pragma unroll
      for (int nt = 0; nt < 4; nt++)
        acc[mt][nt] = mfma16(aF[mt], bF[nt], acc[mt][nt]);
    __syncthreads();
    cur ^= 1;
  }
  float ub[4];
#pragma unroll
  for (int nt = 0; nt < 4; nt++) ub[nt] = up_b[bn + wc * 64 + nt * 16 + m];
#pragma unroll
  for (int mt = 0; mt < 4; mt++)
#pragma unroll
    for (int rr = 0; rr < 4; rr++) {
      int t = bm + wr * 64 + mt * 16 + gq * 4 + rr;
      int b = t / 2304, rem = t - b * 2304;
      int ih = rem / 48, iw = rem - ih * 48;
      int h = 2 * ih + kh, w = 2 * iw + kw;
      size_t tok = ((size_t)b * 96 + h) * 96 + w;
#pragma unroll
      for (int nt = 0; nt < 4; nt++) {
        int ch = bn + wc * 64 + nt * 16 + m;
        sc[tok * 256 + ch] = f2b(acc[mt][nt][rr] + ub[nt]);
      }
    }
}

// ====== K2Y: skip 1x1 GEMM raster (M=73728,N=256,K=256) + y + LN1 partials ====
__global__ __launch_bounds__(256) void k2y(
    const u16* W, const u16* skt, const u16* sc, u16* ybuf, float* pstat) {
  __shared__ __align__(16) u16 Ab[2][4096];
  __shared__ __align__(16) u16 Bb[2][4096];
  int tid = threadIdx.x;
  int lane = tid & 63, wave = tid >> 6;
  int m = lane & 15, gq = lane >> 4;
  int wr = wave >> 1, wc = wave & 1;
  int bm = blockIdx.x * 128, bn = blockIdx.y * 128;
  const u16* Ag = skt + (size_t)bm * 256;
  const u16* Bg = W + WSKIP + (size_t)bn * 256;
  f32x4 acc[4][4] = {};
#pragma unroll
  for (int c = 0; c < 2; c++) {
    int flat = (wave * 2 + c) * 512 + lane * 8;
    int r = flat >> 5, cc = flat & 31;
    GLL(Ag + (size_t)r * 256 + cc, &Ab[0][(wave * 2 + c) * 512]);
    GLL(Bg + (size_t)r * 256 + cc, &Bb[0][(wave * 2 + c) * 512]);
  }
  __syncthreads();
  int cur = 0;
  for (int ki = 0; ki < 8; ki++) {
    if (ki < 7) {
      int kk = (ki + 1) * 32;
#pragma unroll
      for (int c = 0; c < 2; c++) {
        int flat = (wave * 2 + c) * 512 + lane * 8;
        int r = flat >> 5, cc = flat & 31;
        GLL(Ag + (size_t)r * 256 + kk + cc, &Ab[cur ^ 1][(wave * 2 + c) * 512]);
        GLL(Bg + (size_t)r * 256 + kk + cc, &Bb[cur ^ 1][(wave * 2 + c) * 512]);
      }
    }
    short8 aF[4], bF[4];
#pragma unroll
    for (int mt = 0; mt < 4; mt++)
      aF[mt] = ld8(&Ab[cur][(wr * 64 + mt * 16 + m) * 32 + gq * 8]);
#pragma unroll
    for (int nt = 0; nt < 4; nt++)
      bF[nt] = ld8(&Bb[cur][(wc * 64 + nt * 16 + m) * 32 + gq * 8]);
#pragma unroll
    for (int mt = 0; mt < 4; mt++)
#pragma unroll
      for (int nt = 0; nt < 4; nt++)
        acc[mt][nt] = mfma16(aF[mt], bF[nt], acc[mt][nt]);
    __syncthreads();
    cur ^= 1;
  }
#pragma unroll
  for (int mt = 0; mt < 4; mt++)
#pragma unroll
    for (int rr = 0; rr < 4; rr++) {
      int tok = bm + wr * 64 + mt * 16 + gq * 4 + rr;
      float s = 0.f, s2 = 0.f;
#pragma unroll
      for (int nt = 0; nt < 4; nt++) {
        int ch = bn + wc * 64 + nt * 16 + m;
        float y = acc[mt][nt][rr] + b2f(sc[(size_t)tok * 256 + ch]);
        ybuf[(size_t)tok * 256 + ch] = f2b(y);
        s += y; s2 += y * y;
      }
#pragma unroll
      for (int off = 1; off < 16; off <<= 1) {
        s += __shfl_xor(s, off);
        s2 += __shfl_xor(s2, off);
      }
      if (m == 0) {
        int pi = (tok * 4 + blockIdx.y * 2 + wc) * 2;
        pstat[pi] = s;
        pstat[pi + 1] = s2;
      }
    }
}

// ====== K_STATFIN: merge 4 partials -> (rstd, rstd*mean) per row ==============
__global__ __launch_bounds__(256) void k_statfin(const float* pstat, float* stat) {
  int row = blockIdx.x * 256 + threadIdx.x;
  float s = 0.f, s2 = 0.f;
#pragma unroll
  for (int j = 0; j < 4; j++) {
    s += pstat[(row * 4 + j) * 2];
    s2 += pstat[(row * 4 + j) * 2 + 1];
  }
  float mean = s * 0.00390625f;
  float var = s2 * 0.00390625f - mean * mean;
  float r = rsqrtf(var + 1e-6f);
  stat[row * 2] = r;
  stat[row * 2 + 1] = r * mean;
}

// ====== K23: fused qkv GEMM + window attention (2-pass qkv, unroll 4) =========
__global__ __launch_bounds__(256) void k23(
    const u16* W, const u16* ybuf, const float* stat, const float* sgb,
    const float* qkv_b, const float* bias_g, u16* obr) {
  __shared__ __align__(16) u16 yl[49 * 264];
  __shared__ __align__(16) u16 pws[4][6144];
  int tid = threadIdx.x;
  int lane = tid & 63, wave = tid >> 6;
  int m = lane & 15, gq = lane >> 4, k0 = gq * 8;
  int blk = blockIdx.x;
  int bimg = blk / 196, wl = blk - bimg * 196;
  int wrow = wl / 14, wcol = wl - wrow * 14;
  int h0 = wrow * 7, w0 = wcol * 7;
  u16* prv = pws[wave];
#pragma unroll
  for (int t = 0; t < 8; t++) {
    u16x4 z = {};
    *reinterpret_cast<u16x4*>(&prv[t * 256 + lane * 4]) = z;
  }
  for (int it = 0; it < 7; it++) {
    int flat = it * 256 + tid;
    if (flat < 1568) {
      int row = flat >> 5, cc = (flat & 31) * 8;
      int hh = h0 + row / 7, ww = w0 + row % 7;
      short8 v = {};
      if (hh < 96 && ww < 96) {
        int ras = (bimg * 96 + hh) * 96 + ww;
        short8 raw = ld8(ybuf + (size_t)ras * 256 + cc);
        float rs = stat[ras * 2], rmu = stat[ras * 2 + 1];
#pragma unroll
        for (int q2 = 0; q2 < 8; q2++) {
          float zz = b2f(((const u16*)&raw)[q2]) * rs - rmu;
          ((u16*)&v)[q2] = f2b(zz);
        }
      }
      *reinterpret_cast<short8*>(&yl[row * 264 + cc]) = v;
    }
  }
  __syncthreads();
  const float scale = 0.1767766952966369f;  // 1/sqrt(32)
#pragma unroll
  for (int hp = 0; hp < 2; hp++) {
    int h = wave * 2 + hp;
    {
      const u16* bb0 = W + WQKV + (size_t)(h * 32 + m) * 256;
      const u16* bb1 = W + WQKV + (size_t)(h * 32 + 16 + m) * 256;
      const u16* bb2 = W + WQKV + (size_t)(256 + h * 32 + m) * 256;
      const u16* bb3 = W + WQKV + (size_t)(256 + h * 32 + 16 + m) * 256;
      f32x4 acc[4][4] = {};
#pragma unroll 4
      for (int ks = 0; ks < 8; ks++) {
        short8 a[4];
#pragma unroll
        for (int mt = 0; mt < 4; mt++) {
          int row = mt * 16 + m; if (row > 48) row = 48;
          a[mt] = ld8(&yl[row * 264 + ks * 32 + k0]);
        }
        short8 b0 = ld8(bb0 + ks * 32 + k0);
        short8 b1 = ld8(bb1 + ks * 32 + k0);
        short8 b2 = ld8(bb2 + ks * 32 + k0);
        short8 b3 = ld8(bb3 + ks * 32 + k0);
#pragma unroll
        for (int mt = 0; mt < 4; mt++) {
          acc[mt][0] = mfma16(a[mt], b0, acc[mt][0]);
          acc[mt][1] = mfma16(a[mt], b1, acc[mt][1]);
          acc[mt][2] = mfma16(a[mt], b2, acc[mt][2]);
          acc[mt][3] = mfma16(a[mt], b3, acc[mt][3]);
        }
      }
#pragma unroll
      for (int nt = 0; nt < 4; nt++) {
        int hd = (nt & 1) * 16 + m;
        int c = (nt >> 1) * 256 + h * 32 + hd;
        float qb_ = qkv_b[c];
        float sb1 = sgb[2816 + c];
        int base = (nt < 2) ? 2048 : 3616;
#pragma unroll
        for (int mt = 0; mt < 4; mt++)
#pragma unroll
          for (int rr = 0; rr < 4; rr++) {
            int row = mt * 16 + gq * 4 + rr;
            if (row >= 49) continue;
            int hh = h0 + row / 7, ww = w0 + row % 7;
            float vf = (hh < 96 && ww < 96) ? 1.f : 0.f;
            prv[base + row * 32 + hd] = f2b(acc[mt][nt][rr] + vf * sb1 + qb_);
          }
      }
    }
    {
      const u16* bb0 = W + WQKV + (size_t)(512 + h * 32 + m) * 256;
      const u16* bb1 = W + WQKV + (size_t)(512 + h * 32 + 16 + m) * 256;
      f32x4 vacc[4][2] = {};
#pragma unroll 4
      for (int ks = 0; ks < 8; ks++) {
        short8 a[4];
#pragma unroll
        for (int mt = 0; mt < 4; mt++) {
          int row = mt * 16 + m; if (row > 48) row = 48;
          a[mt] = ld8(&yl[row * 264 + ks * 32 + k0]);
        }
        short8 b0 = ld8(bb0 + ks * 32 + k0);
        short8 b1 = ld8(bb1 + ks * 32 + k0);
#pragma unroll
        for (int mt = 0; mt < 4; mt++) {
          vacc[mt][0] = mfma16(a[mt], b0, vacc[mt][0]);
          vacc[mt][1] = mfma16(a[mt], b1, vacc[mt][1]);
        }
      }
      int vsw = (m & 7) * 8;
#pragma unroll
      for (int nv = 0; nv < 2; nv++) {
        int hd = nv * 16 + m;
        int c = 512 + h * 32 + hd;
        float qb_ = qkv_b[c];
        float sb1 = sgb[2816 + c];
#pragma unroll
        for (int mt = 0; mt < 4; mt++)
#pragma unroll
          for (int rr = 0; rr < 4; rr++) {
            int row = mt * 16 + gq * 4 + rr;
            if (row >= 49) continue;
            int hh = h0 + row / 7, ww = w0 + row % 7;
            float vf = (hh < 96 && ww < 96) ? 1.f : 0.f;
            prv[hd * 64 + (row ^ vsw)] = f2b(vacc[mt][nv][rr] + vf * sb1 + qb_);
          }
      }
    }
    short8 aq[4], bk[4];
#pragma unroll
    for (int mt = 0; mt < 4; mt++) { int i = mt * 16 + m; if (i > 48) i = 48; aq[mt] = ld8(&prv[2048 + i * 32 + k0]); }
#pragma unroll
    for (int nt = 0; nt < 4; nt++) { int j = nt * 16 + m; if (j > 48) j = 48; bk[nt] = ld8(&prv[3616 + j * 32 + k0]); }
    f32x4 s[4][4] = {};
#pragma unroll
    for (int mt = 0; mt < 4; mt++)
#pragma unroll
      for (int nt = 0; nt < 4; nt++)
        s[mt][nt] = mfma16(aq[mt], bk[nt], s[mt][nt]);
    const float* BI = bias_g + h * 4096;
    float rsum[4][4];
#pragma unroll
    for (int mt = 0; mt < 4; mt++)
#pragma unroll
      for (int rr = 0; rr < 4; rr++) {
        int i = mt * 16 + gq * 4 + rr;
        float sv[4];
        float mx = -1e38f;
#pragma unroll
        for (int nt = 0; nt < 4; nt++) {
          sv[nt] = s[mt][nt][rr] * scale + BI[i * 64 + nt * 16 + m];
          mx = fmaxf(mx, sv[nt]);
        }
        mx = fmaxf(mx, __shfl_xor(mx, 1));
        mx = fmaxf(mx, __shfl_xor(mx, 2));
        mx = fmaxf(mx, __shfl_xor(mx, 4));
        mx = fmaxf(mx, __shfl_xor(mx, 8));
        float sum = 0.f;
#pragma unroll
        for (int nt = 0; nt < 4; nt++) { sv[nt] = __expf(sv[nt] - mx); sum += sv[nt]; }
        sum += __shfl_xor(sum, 1);
        sum += __shfl_xor(sum, 2);
        sum += __shfl_xor(sum, 4);
        sum += __shfl_xor(sum, 8);
        rsum[mt][rr] = sum;
        int isw = (i & 7) * 8;
#pragma unroll
        for (int nt = 0; nt < 4; nt++) {
          int j = nt * 16 + m;
          prv[2048 + i * 64 + (j ^ isw)] = f2b(sv[nt]);
        }
      }
    f32x4 o[4][2] = {};
#pragma unroll
    for (int ks = 0; ks < 2; ks++) {
      short8 bv[2];
#pragma unroll
      for (int nt = 0; nt < 2; nt++) {
        int hd = nt * 16 + m;
        bv[nt] = ld8(&prv[hd * 64 + ((ks * 32 + k0) ^ ((hd & 7) * 8))]);
      }
#pragma unroll
      for (int mt = 0; mt < 4; mt++) {
        int i = mt * 16 + m;
        short8 ap = *reinterpret_cast<const short8*>(
            &prv[2048 + i * 64 + ((ks * 32 + k0) ^ ((i & 7) * 8))]);
#pragma unroll
        for (int nt = 0; nt < 2; nt++)
          o[mt][nt] = mfma16(ap, bv[nt], o[mt][nt]);
      }
    }
#pragma unroll
    for (int mt = 0; mt < 4; mt++)
#pragma unroll
      for (int rr = 0; rr < 4; rr++) {
        int i = mt * 16 + gq * 4 + rr;
        if (i >= 49) continue;
        int hh = h0 + i / 7, ww = w0 + i % 7;
        if (hh >= 96 || ww >= 96) continue;
        size_t ras = ((size_t)bimg * 96 + hh) * 96 + ww;
        float rinv = 1.f / rsum[mt][rr];
#pragma unroll
        for (int nt = 0; nt < 2; nt++) {
          int c = h * 32 + nt * 16 + m;
          obr[ras * 256 + c] = f2b(o[mt][nt][rr] * rinv);
        }
      }
  }
}

// ====== K4R: proj GEMM raster (M=73728,N=256,K=256) + shortcut + LN2 partials =
__global__ __launch_bounds__(256) void k4r(
    const u16* W, const u16* obr, const float* proj_b, u16* sc, float* pstat) {
  __shared__ __align__(16) u16 Ab[2][4096];
  __shared__ __align__(16) u16 Bb[2][4096];
  int tid = threadIdx.x;
  int lane = tid & 63, wave = tid >> 6;
  int m = lane & 15, gq = lane >> 4;
  int wr = wave >> 1, wc = wave & 1;
  int bm = blockIdx.x * 128, bn = blockIdx.y * 128;
  const u16* Ag = obr + (size_t)bm * 256;
  const u16* Bg = W + WPROJ + (size_t)bn * 256;
  f32x4 acc[4][4] = {};
#pragma unroll
  for (int c = 0; c < 2; c++) {
    int flat = (wave * 2 + c) * 512 + lane * 8;
    int r = flat >> 5, cc = flat & 31;
    GLL(Ag + (size_t)r * 256 + cc, &Ab[0][(wave * 2 + c) * 512]);
    GLL(Bg + (size_t)r * 256 + cc, &Bb[0][(wave * 2 + c) * 512]);
  }
  __syncthreads();
  int cur = 0;
  for (int ki = 0; ki < 8; ki++) {
    if (ki < 7) {
      int kk = (ki + 1) * 32;
#pragma unroll
      for (int c = 0; c < 2; c++) {
        int flat = (wave * 2 + c) * 512 + lane * 8;
        int r = flat >> 5, cc = flat & 31;
        GLL(Ag + (size_t)r * 256 + kk + cc, &Ab[cur ^ 1][(wave * 2 + c) * 512]);
        GLL(Bg + (size_t)r * 256 + kk + cc, &Bb[cur ^ 1][(wave * 2 + c) * 512]);
      }
    }
    short8 aF[4], bF[4];
#pragma unroll
    for (int mt = 0; mt < 4; mt++)
      aF[mt] = ld8(&Ab[cur][(wr * 64 + mt * 16 + m) * 32 + gq * 8]);
#pragma unroll
    for (int nt = 0; nt < 4; nt++)
      bF[nt] = ld8(&Bb[cur][(wc * 64 + nt * 16 + m) * 32 + gq * 8]);
#pragma unroll
    for (int mt = 0; mt < 4; mt++)
#pragma unroll
      for (int nt = 0; nt < 4; nt++)
        acc[mt][nt] = mfma16(aF[mt], bF[nt], acc[mt][nt]);
    __syncthreads();
    cur ^= 1;
  }
#pragma unroll
  for (int mt = 0; mt < 4; mt++)
#pragma unroll
    for (int rr = 0; rr < 4; rr++) {
      int tok = bm + wr * 64 + mt * 16 + gq * 4 + rr;
      float s = 0.f, s2 = 0.f;
#pragma unroll
      for (int nt = 0; nt < 4; nt++) {
        int ch = bn + wc * 64 + nt * 16 + m;
        float v = acc[mt][nt][rr] + proj_b[ch] + b2f(sc[(size_t)tok * 256 + ch]);
        sc[(size_t)tok * 256 + ch] = f2b(v);
        s += v; s2 += v * v;
      }
#pragma unroll
      for (int off = 1; off < 16; off <<= 1) {
        s += __shfl_xor(s, off);
        s2 += __shfl_xor(s2, off);
      }
      if (m == 0) {
        int pi = (tok * 4 + blockIdx.y * 2 + wc) * 2;
        pstat[pi] = s;
        pstat[pi + 1] = s2;
      }
    }
}

// ====== K56: fused LN2+mlp1+GELU+mlp2+residual+NCHW out (64-token tile) =======
// grid 1152. XA[64][264]; HC[64][136]; ot f32[128][66] overlays XA.
// Cross-chunk mlp1-B prefetch + intra-chunk mlp2-B (ks 0..1) prefetch.
__global__ __launch_bounds__(256) void k56(
    const u16* W, const u16* x2, const float* stat, const float* sgb,
    const float* mb1, const float* mb2, float* out) {
  __shared__ __align__(16) u16 XA[64 * 264];
  __shared__ __align__(16) u16 HC[64 * 136];
  int tid = threadIdx.x;
  int lane = tid & 63, wave = tid >> 6;
  int m = lane & 15, gq = lane >> 4, k0 = gq * 8;
  int tok0 = blockIdx.x * 64;
  // stage x2 tile -> XA
#pragma unroll
  for (int it = 0; it < 8; it++) {
    int flat = it * 2048 + tid * 8;
    int row = flat >> 8, col = flat & 255;
    *reinterpret_cast<short8*>(&XA[row * 264 + col]) =
        ld8(x2 + (size_t)(tok0 + row) * 256 + col);
  }
  // hoist LN2 stats for this thread's 16 tokens
  float rsv[4][4], rmuv[4][4];
#pragma unroll
  for (int mt = 0; mt < 4; mt++)
#pragma unroll
    for (int rr = 0; rr < 4; rr++) {
      int tok = tok0 + mt * 16 + gq * 4 + rr;
      rsv[mt][rr] = stat[tok * 2];
      rmuv[mt][rr] = stat[tok * 2 + 1];
    }
  // prefetch chunk 0's mlp1-B for ks 0..3 (32 VGPR)
  short8 pb0[4], pb1[4];
  {
    const u16* Ba = W + WM1 + (size_t)(wave * 32 + m) * 256;
    const u16* Bb = W + WM1 + (size_t)(wave * 32 + 16 + m) * 256;
#pragma unroll
    for (int ks = 0; ks < 4; ks++) {
      pb0[ks] = ld8(Ba + ks * 32 + k0);
      pb1[ks] = ld8(Bb + ks * 32 + k0);
    }
  }
  __syncthreads();
  f32x4 acc2[4][4] = {};  // mlp2 accumulator, persists across chunks
  for (int c = 0; c < 8; c++) {
    // mlp1: N=128 chunk; wave owns 32 cols; ks 0..3 use prefetched B
    const u16* B1a = W + WM1 + (size_t)(c * 128 + wave * 32 + m) * 256;
    const u16* B1b = W + WM1 + (size_t)(c * 128 + wave * 32 + 16 + m) * 256;
    f32x4 acc1[4][2] = {};
#pragma unroll
    for (int ks = 0; ks < 8; ks++) {
      short8 a[4];
#pragma unroll
      for (int mt = 0; mt < 4; mt++)
        a[mt] = ld8(&XA[(mt * 16 + m) * 264 + ks * 32 + k0]);
      short8 b0 = (ks < 4) ? pb0[ks] : ld8(B1a + ks * 32 + k0);
      short8 b1 = (ks < 4) ? pb1[ks] : ld8(B1b + ks * 32 + k0);
#pragma unroll
      for (int mt = 0; mt < 4; mt++) {
        acc1[mt][0] = mfma16(a[mt], b0, acc1[mt][0]);
        acc1[mt][1] = mfma16(a[mt], b1, acc1[mt][1]);
      }
    }
    // issue next chunk's mlp1-B prefetch NOW (hides under GELU+barriers+mlp2)
    if (c < 7) {
      const u16* nBa = W + WM1 + (size_t)((c + 1) * 128 + wave * 32 + m) * 256;
      const u16* nBb = W + WM1 + (size_t)((c + 1) * 128 + wave * 32 + 16 + m) * 256;
#pragma unroll
      for (int ks = 0; ks < 4; ks++) {
        pb0[ks] = ld8(nBa + ks * 32 + k0);
        pb1[ks] = ld8(nBb + ks * 32 + k0);
      }
    }
    // issue this chunk's mlp2-B prefetch for ks 0..1 (hides under GELU+barrier)
    short8 pf2[2][4];
#pragma unroll
    for (int ks = 0; ks < 2; ks++)
#pragma unroll
      for (int nt = 0; nt < 4; nt++) {
        int ch = wave * 64 + nt * 16 + m;
        pf2[ks][nt] = ld8(W + WM2 + (size_t)ch * 1024 + c * 128 + ks * 32 + k0);
      }
    // LN2 fold + fast GELU (x * sigmoid(1.5957692(x + 0.044715x^3))) -> HC
#pragma unroll
    for (int nt = 0; nt < 2; nt++) {
      int col = wave * 32 + nt * 16 + m;
      int ch = c * 128 + col;
      float sg = sgb[ch], sb = sgb[1024 + ch], b1v = mb1[ch];
#pragma unroll
      for (int mt = 0; mt < 4; mt++)
#pragma unroll
        for (int rr = 0; rr < 4; rr++) {
          int tl = mt * 16 + gq * 4 + rr;
          float v = rsv[mt][rr] * acc1[mt][nt][rr] - rmuv[mt][rr] * sg + sb + b1v;
          float u = v * v;
          float y = v * __builtin_fmaf(0.07135481627f, u, 1.595769122f);
          float g = v / (1.f + __expf(-y));
          HC[tl * 136 + col] = f2b(g);
        }
    }
    __syncthreads();
    // mlp2 partial: K=128 (4 steps); ks 0..1 use prefetched B
#pragma unroll
    for (int ks = 0; ks < 4; ks++) {
      short8 a2[4];
#pragma unroll
      for (int mt = 0; mt < 4; mt++)
        a2[mt] = ld8(&HC[(mt * 16 + m) * 136 + ks * 32 + k0]);
      short8 bF[4];
#pragma unroll
      for (int nt = 0; nt < 4; nt++) {
        int ch = wave * 64 + nt * 16 + m;
        bF[nt] = (ks < 2) ? pf2[ks][nt]
                          : ld8(W + WM2 + (size_t)ch * 1024 + c * 128 + ks * 32 + k0);
      }
#pragma unroll
      for (int mt = 0; mt < 4; mt++)
#pragma unroll
        for (int nt = 0; nt < 4; nt++)
          acc2[mt][nt] = mfma16(a2[mt], bF[nt], acc2[mt][nt]);
    }
    __syncthreads();  // before next chunk overwrites HC
  }
  // epilogue: + mb2 + residual (from XA), then NCHW out via ot halves
#pragma unroll
  for (int nt = 0; nt < 4; nt++) {
    int ch = wave * 64 + nt * 16 + m;
    float bias = mb2[ch];
#pragma unroll
    for (int mt = 0; mt < 4; mt++)
#pragma unroll
      for (int rr = 0; rr < 4; rr++) {
        int tl = mt * 16 + gq * 4 + rr;
        acc2[mt][nt][rr] += bias + b2f(XA[tl * 264 + ch]);
      }
  }
  __syncthreads();  // done with XA; reuse as ot
  float* ot = (float*)XA;  // [128][66] f32 = 33,792 B == sizeof(XA)
  int tg = tok0;
  int bimg = tg / 9216, hw0 = tg % 9216;
#pragma unroll
  for (int half = 0; half < 2; half++) {
    if ((wave >> 1) == half) {
#pragma unroll
      for (int nt = 0; nt < 4; nt++) {
        int jj = (wave & 1) * 64 + nt * 16 + m;  // 0..127 within half
#pragma unroll
        for (int mt = 0; mt < 4; mt++)
#pragma unroll
          for (int rr = 0; rr < 4; rr++) {
            int tl = mt * 16 + gq * 4 + rr;
            ot[jj * 66 + tl] = acc2[mt][nt][rr];
          }
      }
    }
    __syncthreads();
    for (int it = 0; it < 32; it++) {
      int flat = it * 256 + tid;
      int j = flat >> 6, t = flat & 63;
      out[((size_t)bimg * 256 + half * 128 + j) * 9216 + hw0 + t] = ot[j * 66 + t];
    }
    __syncthreads();
  }
}

extern "C" void kernel_launch(void* const* d_in, const int* in_sizes, int n_in,
                              void* d_out, int out_size, void* d_ws, size_t ws_size,
                              hipStream_t stream) {
  const float* x      = (const float*)d_in[0];
  const float* skipf  = (const float*)d_in[1];
  const float* up_w   = (const float*)d_in[2];
  const float* up_b   = (const float*)d_in[3];
  const float* skip_w = (const float*)d_in[4];
  const float* g1     = (const float*)d_in[5];
  const float* be1    = (const float*)d_in[6];
  const float* qkv_w  = (const float*)d_in[7];
  const float* qkv_b  = (const float*)d_in[8];
  const float* rpb    = (const float*)d_in[9];
  const float* proj_w = (const float*)d_in[10];
  const float* proj_b = (const float*)d_in[11];
  const float* g2     = (const float*)d_in[12];
  const float* be2    = (const float*)d_in[13];
  const float* m_w1   = (const float*)d_in[14];
  const float* m_b1   = (const float*)d_in[15];
  const float* m_w2   = (const float*)d_in[16];
  const float* m_b2   = (const float*)d_in[17];
  if (ws_size < WS_NEED) {
    k_sentinel<<<1, 256, 0, stream>>>((float*)d_out);
    return;
  }
  char* ws = (char*)d_ws;
  u16*   W    = (u16*)ws;
  float* bias = (float*)(ws + OFF_BIAS);
  u16*   sc   = (u16*)(ws + OFF_SC);
  u16*   xt   = (u16*)(ws + OFF_OVR);
  u16*   skt  = (u16*)(ws + OFF_OVR);
  float* stat = (float*)(ws + OFF_STAT);
  float* pst  = (float*)(ws + OFF_PST);
  float* sgb  = (float*)(ws + OFF_SGB);
  u16*   ybuf = (u16*)d_out;
  u16*   obr  = (u16*)((char*)d_out + 37748736u);

  k_prep<<<5504, 256, 0, stream>>>(qkv_w, proj_w, m_w1, m_w2, skip_w, up_w, rpb,
                                   g1, g2, W, bias);
  k_fold<<<704, 256, 0, stream>>>(m_w1, qkv_w, g1, be1, g2, be2, sgb);
  k_tr<<<dim3(72, 16, 8), 256, 0, stream>>>(x, xt, 512, 2304);
  k1g<<<dim3(144, 2, 4), 256, 0, stream>>>(W, xt, up_b, sc);
  k_tr_skip<<<dim3(3, 8, 768), 256, 0, stream>>>(skipf, skt);
  k2y<<<dim3(576, 2), 256, 0, stream>>>(W, skt, sc, ybuf, pst);
  k_statfin<<<288, 256, 0, stream>>>(pst, stat);
  k23<<<1568, 256, 0, stream>>>(W, ybuf, stat, sgb, qkv_b, bias, obr);
  k4r<<<dim3(576, 2), 256, 0, stream>>>(W, obr, proj_b, sc, pst);
  k_statfin<<<288, 256, 0, stream>>>(pst, stat);
  k56<<<1152, 256, 0, stream>>>(W, sc, stat, sgb, m_b1, m_b2, (float*)d_out);
}

// Round 22
// 558.335 us; speedup vs baseline: 1.1326x; 1.1326x over previous
//
#include <hip/hip_runtime.h>

typedef __attribute__((ext_vector_type(8))) short short8;
typedef __attribute__((ext_vector_type(4))) float f32x4;
typedef __attribute__((ext_vector_type(4))) unsigned short u16x4;
typedef unsigned short u16;
typedef unsigned int u32;

#define DEV static __device__ __forceinline__

DEV u16 f2b(float f) {
  u32 u = __builtin_bit_cast(u32, f);
  return (u16)((u + 0x7fffu + ((u >> 16) & 1u)) >> 16);
}
DEV float b2f(u16 h) {
  u32 u = ((u32)h) << 16;
  return __builtin_bit_cast(float, u);
}
DEV short8 ld8(const u16* p) { return *reinterpret_cast<const short8*>(p); }
DEV f32x4 mfma16(short8 a, short8 b, f32x4 c) {
  return __builtin_amdgcn_mfma_f32_16x16x32_bf16(a, b, c, 0, 0, 0);
}
DEV float wredsum(float v) {
#pragma unroll
  for (int off = 1; off < 64; off <<= 1) v += __shfl_xor(v, off);
  return v;
}

#define GLL(gp, lp) __builtin_amdgcn_global_load_lds( \
    (const __attribute__((address_space(1))) void*)(gp), \
    (__attribute__((address_space(3))) void*)(lp), 16, 0, 0)

// ---- weight arena (u16 element offsets) ----
#define WQKV   0         // [768][256]  (pre-scaled by gamma1)
#define WPROJ  196608    // [256][256]
#define WM1    262144    // [1024][256] (pre-scaled by gamma2)
#define WM2    524288    // [256][1024]
#define WSKIP  786432    // [256][256]
#define WUP    851968    // [4][256][512]  kk = kh*2+kw

// ---- ws byte offsets ----
#define OFF_BIAS 2752512u
#define OFF_SC   2883584u     // bf16 sc: conv shortcut -> x2 [73728][256]
#define OFF_OVR  40632320u    // overlay:
// phase A: xt @OVR (18,874,368)  [dead after k1g]
// phase B: skt @OVR (37,748,736) [dead after k2y]
// persistent: stat @+52,000,000; pstat @+52,600,000; sgb @+55,000,000
#define OFF_STAT (OFF_OVR + 52000000u)
#define OFF_PST  (OFF_OVR + 52600000u)
#define OFF_SGB  (OFF_OVR + 55000000u)
// d_out scratch: ybuf u16 @0 (37,748,736); obr u16 @37,748,736 (37,748,736)
#define WS_NEED  96227328u

__global__ void k_sentinel(float* out) { out[threadIdx.x] = 31337.0f; }

// ================= prep: weights -> bf16, bias table =========================
__global__ __launch_bounds__(256) void k_prep(
    const float* qkv_w, const float* proj_w, const float* mlp_w1,
    const float* mlp_w2, const float* skip_w, const float* up_w,
    const float* rpb, const float* g1, const float* g2, u16* W, float* bias_g) {
  int i = blockIdx.x * 256 + threadIdx.x;
  if (i < 196608) { W[WQKV + i] = f2b(qkv_w[i] * g1[i & 255]); return; }
  i -= 196608;
  if (i < 65536) { W[WPROJ + i] = f2b(proj_w[i]); return; }
  i -= 65536;
  if (i < 262144) { W[WM1 + i] = f2b(mlp_w1[i] * g2[i & 255]); return; }
  i -= 262144;
  if (i < 262144) { W[WM2 + i] = f2b(mlp_w2[i]); return; }
  i -= 262144;
  if (i < 65536) { W[WSKIP + i] = f2b(skip_w[i]); return; }
  i -= 65536;
  if (i < 524288) {
    int ci = i & 511; int rest = i >> 9; int co = rest & 255; int kk = rest >> 8;
    W[WUP + i] = f2b(up_w[ci * 1024 + co * 4 + kk]);
    return;
  }
  i -= 524288;
  if (i < 32768) {
    int h = i >> 12, r = i & 4095, ii = r >> 6, j = r & 63;
    float v;
    if (j >= 49) v = -1e30f;
    else if (ii >= 49) v = 0.f;
    else {
      int d0 = (ii / 7 - j / 7) + 6, d1 = (ii % 7 - j % 7) + 6;
      v = rpb[(d0 * 13 + d1) * 8 + h];
    }
    bias_g[i] = v;
  }
}

// ====== K_FOLD: wave-parallel fold dot-products (Sg2, Sb2, Sb1) ===============
__global__ __launch_bounds__(256) void k_fold(
    const float* mlp_w1, const float* qkv_w, const float* g1, const float* be1,
    const float* g2, const float* be2, float* sgb) {
  int wave = threadIdx.x >> 6, lane = threadIdx.x & 63;
  int id = blockIdx.x * 4 + wave;
  const float* wsrc;
  const float* vec;
  int out;
  if (id < 1024) { wsrc = mlp_w1 + (size_t)id * 256; vec = g2; out = id; }
  else if (id < 2048) { wsrc = mlp_w1 + (size_t)(id - 1024) * 256; vec = be2; out = id; }
  else { wsrc = qkv_w + (size_t)(id - 2048) * 256; vec = be1; out = 2816 + (id - 2048); }
  float s = 0.f;
#pragma unroll
  for (int j = 0; j < 4; j++) {
    int k = j * 64 + lane;
    s += vec[k] * wsrc[k];
  }
  s = wredsum(s);
  if (lane == 0) sgb[out] = s;
}

// ============== NCHW f32 -> NHWC bf16 tiled transpose (for x) =================
__global__ __launch_bounds__(256) void k_tr(const float* src, u16* dst, int C, int HW) {
  __shared__ float t[32][33];
  int hw0 = blockIdx.x * 32, c0 = blockIdx.y * 32, b = blockIdx.z;
  int tx = threadIdx.x & 31, ty = threadIdx.x >> 5;
  const float* s = src + (size_t)b * C * HW;
  u16* d = dst + (size_t)b * C * HW;
#pragma unroll
  for (int i = 0; i < 4; i++)
    t[ty + i * 8][tx] = s[(size_t)(c0 + ty + i * 8) * HW + hw0 + tx];
  __syncthreads();
#pragma unroll
  for (int i = 0; i < 4; i++)
    d[(size_t)(hw0 + ty + i * 8) * C + c0 + tx] = f2b(t[tx][ty + i * 8]);
}

// ===== batched skip transpose: skip[b][c][h][w] -> skt[b][h][w][c] (bf16) =====
__global__ __launch_bounds__(256) void k_tr_skip(const float* src, u16* dst) {
  __shared__ float t[32][33];
  int w0 = blockIdx.x * 32, c0 = blockIdx.y * 32;
  int z = blockIdx.z;
  int b = z / 96, h = z - b * 96;
  int tx = threadIdx.x & 31, ty = threadIdx.x >> 5;
  const float* s = src + (size_t)b * 256 * 9216 + (size_t)h * 96;
  u16* d = dst + (((size_t)b * 96 + h) * 96) * 256;
#pragma unroll
  for (int i = 0; i < 4; i++)
    t[ty + i * 8][tx] = s[(size_t)(c0 + ty + i * 8) * 9216 + w0 + tx];
  __syncthreads();
#pragma unroll
  for (int i = 0; i < 4; i++)
    d[(size_t)(w0 + ty + i * 8) * 256 + c0 + tx] = f2b(t[tx][ty + i * 8]);
}

// ====== K1G: convT as GEMM (M=18432,N=256,K=512) x4 parities, dbuf gll ========
__global__ __launch_bounds__(256) void k1g(
    const u16* W, const u16* xt, const float* up_b, u16* sc) {
  __shared__ __align__(16) u16 Ab[2][4096];
  __shared__ __align__(16) u16 Bb[2][4096];
  int tid = threadIdx.x;
  int lane = tid & 63, wave = tid >> 6;
  int m = lane & 15, gq = lane >> 4;
  int wr = wave >> 1, wc = wave & 1;
  int bm = blockIdx.x * 128, bn = blockIdx.y * 128;
  int kk = blockIdx.z, kh = kk >> 1, kw = kk & 1;
  const u16* Ag = xt + (size_t)bm * 512;
  const u16* Bg = W + WUP + (size_t)kk * 131072 + (size_t)bn * 512;
  f32x4 acc[4][4] = {};
#pragma unroll
  for (int c = 0; c < 2; c++) {
    int flat = (wave * 2 + c) * 512 + lane * 8;
    int r = flat >> 5, cc = flat & 31;
    GLL(Ag + (size_t)r * 512 + cc, &Ab[0][(wave * 2 + c) * 512]);
    GLL(Bg + (size_t)r * 512 + cc, &Bb[0][(wave * 2 + c) * 512]);
  }
  __syncthreads();
  int cur = 0;
  for (int ki = 0; ki < 16; ki++) {
    if (ki < 15) {
      int kkk = (ki + 1) * 32;
#pragma unroll
      for (int c = 0; c < 2; c++) {
        int flat = (wave * 2 + c) * 512 + lane * 8;
        int r = flat >> 5, cc = flat & 31;
        GLL(Ag + (size_t)r * 512 + kkk + cc, &Ab[cur ^ 1][(wave * 2 + c) * 512]);
        GLL(Bg + (size_t)r * 512 + kkk + cc, &Bb[cur ^ 1][(wave * 2 + c) * 512]);
      }
    }
    short8 aF[4], bF[4];
#pragma unroll
    for (int mt = 0; mt < 4; mt++)
      aF[mt] = ld8(&Ab[cur][(wr * 64 + mt * 16 + m) * 32 + gq * 8]);
#pragma unroll
    for (int nt = 0; nt < 4; nt++)
      bF[nt] = ld8(&Bb[cur][(wc * 64 + nt * 16 + m) * 32 + gq * 8]);
#pragma unroll
    for (int mt = 0; mt < 4; mt++)
#pragma unroll
      for (int nt = 0; nt < 4; nt++)
        acc[mt][nt] = mfma16(aF[mt], bF[nt], acc[mt][nt]);
    __syncthreads();
    cur ^= 1;
  }
  float ub[4];
#pragma unroll
  for (int nt = 0; nt < 4; nt++) ub[nt] = up_b[bn + wc * 64 + nt * 16 + m];
#pragma unroll
  for (int mt = 0; mt < 4; mt++)
#pragma unroll
    for (int rr = 0; rr < 4; rr++) {
      int t = bm + wr * 64 + mt * 16 + gq * 4 + rr;
      int b = t / 2304, rem = t - b * 2304;
      int ih = rem / 48, iw = rem - ih * 48;
      int h = 2 * ih + kh, w = 2 * iw + kw;
      size_t tok = ((size_t)b * 96 + h) * 96 + w;
#pragma unroll
      for (int nt = 0; nt < 4; nt++) {
        int ch = bn + wc * 64 + nt * 16 + m;
        sc[tok * 256 + ch] = f2b(acc[mt][nt][rr] + ub[nt]);
      }
    }
}

// ====== K2Y: skip 1x1 GEMM raster (M=73728,N=256,K=256) + y + LN1 partials ====
__global__ __launch_bounds__(256) void k2y(
    const u16* W, const u16* skt, const u16* sc, u16* ybuf, float* pstat) {
  __shared__ __align__(16) u16 Ab[2][4096];
  __shared__ __align__(16) u16 Bb[2][4096];
  int tid = threadIdx.x;
  int lane = tid & 63, wave = tid >> 6;
  int m = lane & 15, gq = lane >> 4;
  int wr = wave >> 1, wc = wave & 1;
  int bm = blockIdx.x * 128, bn = blockIdx.y * 128;
  const u16* Ag = skt + (size_t)bm * 256;
  const u16* Bg = W + WSKIP + (size_t)bn * 256;
  f32x4 acc[4][4] = {};
#pragma unroll
  for (int c = 0; c < 2; c++) {
    int flat = (wave * 2 + c) * 512 + lane * 8;
    int r = flat >> 5, cc = flat & 31;
    GLL(Ag + (size_t)r * 256 + cc, &Ab[0][(wave * 2 + c) * 512]);
    GLL(Bg + (size_t)r * 256 + cc, &Bb[0][(wave * 2 + c) * 512]);
  }
  __syncthreads();
  int cur = 0;
  for (int ki = 0; ki < 8; ki++) {
    if (ki < 7) {
      int kk = (ki + 1) * 32;
#pragma unroll
      for (int c = 0; c < 2; c++) {
        int flat = (wave * 2 + c) * 512 + lane * 8;
        int r = flat >> 5, cc = flat & 31;
        GLL(Ag + (size_t)r * 256 + kk + cc, &Ab[cur ^ 1][(wave * 2 + c) * 512]);
        GLL(Bg + (size_t)r * 256 + kk + cc, &Bb[cur ^ 1][(wave * 2 + c) * 512]);
      }
    }
    short8 aF[4], bF[4];
#pragma unroll
    for (int mt = 0; mt < 4; mt++)
      aF[mt] = ld8(&Ab[cur][(wr * 64 + mt * 16 + m) * 32 + gq * 8]);
#pragma unroll
    for (int nt = 0; nt < 4; nt++)
      bF[nt] = ld8(&Bb[cur][(wc * 64 + nt * 16 + m) * 32 + gq * 8]);
#pragma unroll
    for (int mt = 0; mt < 4; mt++)
#pragma unroll
      for (int nt = 0; nt < 4; nt++)
        acc[mt][nt] = mfma16(aF[mt], bF[nt], acc[mt][nt]);
    __syncthreads();
    cur ^= 1;
  }
#pragma unroll
  for (int mt = 0; mt < 4; mt++)
#pragma unroll
    for (int rr = 0; rr < 4; rr++) {
      int tok = bm + wr * 64 + mt * 16 + gq * 4 + rr;
      float s = 0.f, s2 = 0.f;
#pragma unroll
      for (int nt = 0; nt < 4; nt++) {
        int ch = bn + wc * 64 + nt * 16 + m;
        float y = acc[mt][nt][rr] + b2f(sc[(size_t)tok * 256 + ch]);
        ybuf[(size_t)tok * 256 + ch] = f2b(y);
        s += y; s2 += y * y;
      }
#pragma unroll
      for (int off = 1; off < 16; off <<= 1) {
        s += __shfl_xor(s, off);
        s2 += __shfl_xor(s2, off);
      }
      if (m == 0) {
        int pi = (tok * 4 + blockIdx.y * 2 + wc) * 2;
        pstat[pi] = s;
        pstat[pi + 1] = s2;
      }
    }
}

// ====== K_STATFIN: merge 4 partials -> (rstd, rstd*mean) per row ==============
__global__ __launch_bounds__(256) void k_statfin(const float* pstat, float* stat) {
  int row = blockIdx.x * 256 + threadIdx.x;
  float s = 0.f, s2 = 0.f;
#pragma unroll
  for (int j = 0; j < 4; j++) {
    s += pstat[(row * 4 + j) * 2];
    s2 += pstat[(row * 4 + j) * 2 + 1];
  }
  float mean = s * 0.00390625f;
  float var = s2 * 0.00390625f - mean * mean;
  float r = rsqrtf(var + 1e-6f);
  stat[row * 2] = r;
  stat[row * 2 + 1] = r * mean;
}

// ====== K23: fused qkv GEMM + window attention (2-pass qkv, unroll 4) =========
__global__ __launch_bounds__(256) void k23(
    const u16* W, const u16* ybuf, const float* stat, const float* sgb,
    const float* qkv_b, const float* bias_g, u16* obr) {
  __shared__ __align__(16) u16 yl[49 * 264];
  __shared__ __align__(16) u16 pws[4][6144];
  int tid = threadIdx.x;
  int lane = tid & 63, wave = tid >> 6;
  int m = lane & 15, gq = lane >> 4, k0 = gq * 8;
  int blk = blockIdx.x;
  int bimg = blk / 196, wl = blk - bimg * 196;
  int wrow = wl / 14, wcol = wl - wrow * 14;
  int h0 = wrow * 7, w0 = wcol * 7;
  u16* prv = pws[wave];
#pragma unroll
  for (int t = 0; t < 8; t++) {
    u16x4 z = {};
    *reinterpret_cast<u16x4*>(&prv[t * 256 + lane * 4]) = z;
  }
  for (int it = 0; it < 7; it++) {
    int flat = it * 256 + tid;
    if (flat < 1568) {
      int row = flat >> 5, cc = (flat & 31) * 8;
      int hh = h0 + row / 7, ww = w0 + row % 7;
      short8 v = {};
      if (hh < 96 && ww < 96) {
        int ras = (bimg * 96 + hh) * 96 + ww;
        short8 raw = ld8(ybuf + (size_t)ras * 256 + cc);
        float rs = stat[ras * 2], rmu = stat[ras * 2 + 1];
#pragma unroll
        for (int q2 = 0; q2 < 8; q2++) {
          float zz = b2f(((const u16*)&raw)[q2]) * rs - rmu;
          ((u16*)&v)[q2] = f2b(zz);
        }
      }
      *reinterpret_cast<short8*>(&yl[row * 264 + cc]) = v;
    }
  }
  __syncthreads();
  const float scale = 0.1767766952966369f;  // 1/sqrt(32)
#pragma unroll
  for (int hp = 0; hp < 2; hp++) {
    int h = wave * 2 + hp;
    {
      const u16* bb0 = W + WQKV + (size_t)(h * 32 + m) * 256;
      const u16* bb1 = W + WQKV + (size_t)(h * 32 + 16 + m) * 256;
      const u16* bb2 = W + WQKV + (size_t)(256 + h * 32 + m) * 256;
      const u16* bb3 = W + WQKV + (size_t)(256 + h * 32 + 16 + m) * 256;
      f32x4 acc[4][4] = {};
#pragma unroll 4
      for (int ks = 0; ks < 8; ks++) {
        short8 a[4];
#pragma unroll
        for (int mt = 0; mt < 4; mt++) {
          int row = mt * 16 + m; if (row > 48) row = 48;
          a[mt] = ld8(&yl[row * 264 + ks * 32 + k0]);
        }
        short8 b0 = ld8(bb0 + ks * 32 + k0);
        short8 b1 = ld8(bb1 + ks * 32 + k0);
        short8 b2 = ld8(bb2 + ks * 32 + k0);
        short8 b3 = ld8(bb3 + ks * 32 + k0);
#pragma unroll
        for (int mt = 0; mt < 4; mt++) {
          acc[mt][0] = mfma16(a[mt], b0, acc[mt][0]);
          acc[mt][1] = mfma16(a[mt], b1, acc[mt][1]);
          acc[mt][2] = mfma16(a[mt], b2, acc[mt][2]);
          acc[mt][3] = mfma16(a[mt], b3, acc[mt][3]);
        }
      }
#pragma unroll
      for (int nt = 0; nt < 4; nt++) {
        int hd = (nt & 1) * 16 + m;
        int c = (nt >> 1) * 256 + h * 32 + hd;
        float qb_ = qkv_b[c];
        float sb1 = sgb[2816 + c];
        int base = (nt < 2) ? 2048 : 3616;
#pragma unroll
        for (int mt = 0; mt < 4; mt++)
#pragma unroll
          for (int rr = 0; rr < 4; rr++) {
            int row = mt * 16 + gq * 4 + rr;
            if (row >= 49) continue;
            int hh = h0 + row / 7, ww = w0 + row % 7;
            float vf = (hh < 96 && ww < 96) ? 1.f : 0.f;
            prv[base + row * 32 + hd] = f2b(acc[mt][nt][rr] + vf * sb1 + qb_);
          }
      }
    }
    {
      const u16* bb0 = W + WQKV + (size_t)(512 + h * 32 + m) * 256;
      const u16* bb1 = W + WQKV + (size_t)(512 + h * 32 + 16 + m) * 256;
      f32x4 vacc[4][2] = {};
#pragma unroll 4
      for (int ks = 0; ks < 8; ks++) {
        short8 a[4];
#pragma unroll
        for (int mt = 0; mt < 4; mt++) {
          int row = mt * 16 + m; if (row > 48) row = 48;
          a[mt] = ld8(&yl[row * 264 + ks * 32 + k0]);
        }
        short8 b0 = ld8(bb0 + ks * 32 + k0);
        short8 b1 = ld8(bb1 + ks * 32 + k0);
#pragma unroll
        for (int mt = 0; mt < 4; mt++) {
          vacc[mt][0] = mfma16(a[mt], b0, vacc[mt][0]);
          vacc[mt][1] = mfma16(a[mt], b1, vacc[mt][1]);
        }
      }
      int vsw = (m & 7) * 8;
#pragma unroll
      for (int nv = 0; nv < 2; nv++) {
        int hd = nv * 16 + m;
        int c = 512 + h * 32 + hd;
        float qb_ = qkv_b[c];
        float sb1 = sgb[2816 + c];
#pragma unroll
        for (int mt = 0; mt < 4; mt++)
#pragma unroll
          for (int rr = 0; rr < 4; rr++) {
            int row = mt * 16 + gq * 4 + rr;
            if (row >= 49) continue;
            int hh = h0 + row / 7, ww = w0 + row % 7;
            float vf = (hh < 96 && ww < 96) ? 1.f : 0.f;
            prv[hd * 64 + (row ^ vsw)] = f2b(vacc[mt][nv][rr] + vf * sb1 + qb_);
          }
      }
    }
    short8 aq[4], bk[4];
#pragma unroll
    for (int mt = 0; mt < 4; mt++) { int i = mt * 16 + m; if (i > 48) i = 48; aq[mt] = ld8(&prv[2048 + i * 32 + k0]); }
#pragma unroll
    for (int nt = 0; nt < 4; nt++) { int j = nt * 16 + m; if (j > 48) j = 48; bk[nt] = ld8(&prv[3616 + j * 32 + k0]); }
    f32x4 s[4][4] = {};
#pragma unroll
    for (int mt = 0; mt < 4; mt++)
#pragma unroll
      for (int nt = 0; nt < 4; nt++)
        s[mt][nt] = mfma16(aq[mt], bk[nt], s[mt][nt]);
    const float* BI = bias_g + h * 4096;
    float rsum[4][4];
#pragma unroll
    for (int mt = 0; mt < 4; mt++)
#pragma unroll
      for (int rr = 0; rr < 4; rr++) {
        int i = mt * 16 + gq * 4 + rr;
        float sv[4];
        float mx = -1e38f;
#pragma unroll
        for (int nt = 0; nt < 4; nt++) {
          sv[nt] = s[mt][nt][rr] * scale + BI[i * 64 + nt * 16 + m];
          mx = fmaxf(mx, sv[nt]);
        }
        mx = fmaxf(mx, __shfl_xor(mx, 1));
        mx = fmaxf(mx, __shfl_xor(mx, 2));
        mx = fmaxf(mx, __shfl_xor(mx, 4));
        mx = fmaxf(mx, __shfl_xor(mx, 8));
        float sum = 0.f;
#pragma unroll
        for (int nt = 0; nt < 4; nt++) { sv[nt] = __expf(sv[nt] - mx); sum += sv[nt]; }
        sum += __shfl_xor(sum, 1);
        sum += __shfl_xor(sum, 2);
        sum += __shfl_xor(sum, 4);
        sum += __shfl_xor(sum, 8);
        rsum[mt][rr] = sum;
        int isw = (i & 7) * 8;
#pragma unroll
        for (int nt = 0; nt < 4; nt++) {
          int j = nt * 16 + m;
          prv[2048 + i * 64 + (j ^ isw)] = f2b(sv[nt]);
        }
      }
    f32x4 o[4][2] = {};
#pragma unroll
    for (int ks = 0; ks < 2; ks++) {
      short8 bv[2];
#pragma unroll
      for (int nt = 0; nt < 2; nt++) {
        int hd = nt * 16 + m;
        bv[nt] = ld8(&prv[hd * 64 + ((ks * 32 + k0) ^ ((hd & 7) * 8))]);
      }
#pragma unroll
      for (int mt = 0; mt < 4; mt++) {
        int i = mt * 16 + m;
        short8 ap = *reinterpret_cast<const short8*>(
            &prv[2048 + i * 64 + ((ks * 32 + k0) ^ ((i & 7) * 8))]);
#pragma unroll
        for (int nt = 0; nt < 2; nt++)
          o[mt][nt] = mfma16(ap, bv[nt], o[mt][nt]);
      }
    }
#pragma unroll
    for (int mt = 0; mt < 4; mt++)
#pragma unroll
      for (int rr = 0; rr < 4; rr++) {
        int i = mt * 16 + gq * 4 + rr;
        if (i >= 49) continue;
        int hh = h0 + i / 7, ww = w0 + i % 7;
        if (hh >= 96 || ww >= 96) continue;
        size_t ras = ((size_t)bimg * 96 + hh) * 96 + ww;
        float rinv = 1.f / rsum[mt][rr];
#pragma unroll
        for (int nt = 0; nt < 2; nt++) {
          int c = h * 32 + nt * 16 + m;
          obr[ras * 256 + c] = f2b(o[mt][nt][rr] * rinv);
        }
      }
  }
}

// ====== K4R: proj GEMM raster (M=73728,N=256,K=256) + shortcut + LN2 partials =
__global__ __launch_bounds__(256) void k4r(
    const u16* W, const u16* obr, const float* proj_b, u16* sc, float* pstat) {
  __shared__ __align__(16) u16 Ab[2][4096];
  __shared__ __align__(16) u16 Bb[2][4096];
  int tid = threadIdx.x;
  int lane = tid & 63, wave = tid >> 6;
  int m = lane & 15, gq = lane >> 4;
  int wr = wave >> 1, wc = wave & 1;
  int bm = blockIdx.x * 128, bn = blockIdx.y * 128;
  const u16* Ag = obr + (size_t)bm * 256;
  const u16* Bg = W + WPROJ + (size_t)bn * 256;
  f32x4 acc[4][4] = {};
#pragma unroll
  for (int c = 0; c < 2; c++) {
    int flat = (wave * 2 + c) * 512 + lane * 8;
    int r = flat >> 5, cc = flat & 31;
    GLL(Ag + (size_t)r * 256 + cc, &Ab[0][(wave * 2 + c) * 512]);
    GLL(Bg + (size_t)r * 256 + cc, &Bb[0][(wave * 2 + c) * 512]);
  }
  __syncthreads();
  int cur = 0;
  for (int ki = 0; ki < 8; ki++) {
    if (ki < 7) {
      int kk = (ki + 1) * 32;
#pragma unroll
      for (int c = 0; c < 2; c++) {
        int flat = (wave * 2 + c) * 512 + lane * 8;
        int r = flat >> 5, cc = flat & 31;
        GLL(Ag + (size_t)r * 256 + kk + cc, &Ab[cur ^ 1][(wave * 2 + c) * 512]);
        GLL(Bg + (size_t)r * 256 + kk + cc, &Bb[cur ^ 1][(wave * 2 + c) * 512]);
      }
    }
    short8 aF[4], bF[4];
#pragma unroll
    for (int mt = 0; mt < 4; mt++)
      aF[mt] = ld8(&Ab[cur][(wr * 64 + mt * 16 + m) * 32 + gq * 8]);
#pragma unroll
    for (int nt = 0; nt < 4; nt++)
      bF[nt] = ld8(&Bb[cur][(wc * 64 + nt * 16 + m) * 32 + gq * 8]);
#pragma unroll
    for (int mt = 0; mt < 4; mt++)
#pragma unroll
      for (int nt = 0; nt < 4; nt++)
        acc[mt][nt] = mfma16(aF[mt], bF[nt], acc[mt][nt]);
    __syncthreads();
    cur ^= 1;
  }
#pragma unroll
  for (int mt = 0; mt < 4; mt++)
#pragma unroll
    for (int rr = 0; rr < 4; rr++) {
      int tok = bm + wr * 64 + mt * 16 + gq * 4 + rr;
      float s = 0.f, s2 = 0.f;
#pragma unroll
      for (int nt = 0; nt < 4; nt++) {
        int ch = bn + wc * 64 + nt * 16 + m;
        float v = acc[mt][nt][rr] + proj_b[ch] + b2f(sc[(size_t)tok * 256 + ch]);
        sc[(size_t)tok * 256 + ch] = f2b(v);
        s += v; s2 += v * v;
      }
#pragma unroll
      for (int off = 1; off < 16; off <<= 1) {
        s += __shfl_xor(s, off);
        s2 += __shfl_xor(s2, off);
      }
      if (m == 0) {
        int pi = (tok * 4 + blockIdx.y * 2 + wc) * 2;
        pstat[pi] = s;
        pstat[pi + 1] = s2;
      }
    }
}

// ====== K56: fused LN2+mlp1+GELU+mlp2+residual+NCHW out (64-token tile) =======
// grid 1152. XA[64][264]; HC[64][136]; ot f32[128][66] overlays XA.
// Cross-chunk mlp1-B prefetch (VGPR 124 — hard cap 128, occupancy cliff).
__global__ __launch_bounds__(256) void k56(
    const u16* W, const u16* x2, const float* stat, const float* sgb,
    const float* mb1, const float* mb2, float* out) {
  __shared__ __align__(16) u16 XA[64 * 264];
  __shared__ __align__(16) u16 HC[64 * 136];
  int tid = threadIdx.x;
  int lane = tid & 63, wave = tid >> 6;
  int m = lane & 15, gq = lane >> 4, k0 = gq * 8;
  int tok0 = blockIdx.x * 64;
  // stage x2 tile -> XA
#pragma unroll
  for (int it = 0; it < 8; it++) {
    int flat = it * 2048 + tid * 8;
    int row = flat >> 8, col = flat & 255;
    *reinterpret_cast<short8*>(&XA[row * 264 + col]) =
        ld8(x2 + (size_t)(tok0 + row) * 256 + col);
  }
  // hoist LN2 stats for this thread's 16 tokens
  float rsv[4][4], rmuv[4][4];
#pragma unroll
  for (int mt = 0; mt < 4; mt++)
#pragma unroll
    for (int rr = 0; rr < 4; rr++) {
      int tok = tok0 + mt * 16 + gq * 4 + rr;
      rsv[mt][rr] = stat[tok * 2];
      rmuv[mt][rr] = stat[tok * 2 + 1];
    }
  // prefetch chunk 0's mlp1-B for ks 0..3 (32 VGPR)
  short8 pb0[4], pb1[4];
  {
    const u16* Ba = W + WM1 + (size_t)(wave * 32 + m) * 256;
    const u16* Bb = W + WM1 + (size_t)(wave * 32 + 16 + m) * 256;
#pragma unroll
    for (int ks = 0; ks < 4; ks++) {
      pb0[ks] = ld8(Ba + ks * 32 + k0);
      pb1[ks] = ld8(Bb + ks * 32 + k0);
    }
  }
  __syncthreads();
  f32x4 acc2[4][4] = {};  // mlp2 accumulator, persists across chunks
  for (int c = 0; c < 8; c++) {
    // mlp1: N=128 chunk; wave owns 32 cols; ks 0..3 use prefetched B
    const u16* B1a = W + WM1 + (size_t)(c * 128 + wave * 32 + m) * 256;
    const u16* B1b = W + WM1 + (size_t)(c * 128 + wave * 32 + 16 + m) * 256;
    f32x4 acc1[4][2] = {};
#pragma unroll
    for (int ks = 0; ks < 8; ks++) {
      short8 a[4];
#pragma unroll
      for (int mt = 0; mt < 4; mt++)
        a[mt] = ld8(&XA[(mt * 16 + m) * 264 + ks * 32 + k0]);
      short8 b0 = (ks < 4) ? pb0[ks] : ld8(B1a + ks * 32 + k0);
      short8 b1 = (ks < 4) ? pb1[ks] : ld8(B1b + ks * 32 + k0);
#pragma unroll
      for (int mt = 0; mt < 4; mt++) {
        acc1[mt][0] = mfma16(a[mt], b0, acc1[mt][0]);
        acc1[mt][1] = mfma16(a[mt], b1, acc1[mt][1]);
      }
    }
    // issue next chunk's B prefetch NOW: latency hides under GELU+barriers+mlp2
    if (c < 7) {
      const u16* nBa = W + WM1 + (size_t)((c + 1) * 128 + wave * 32 + m) * 256;
      const u16* nBb = W + WM1 + (size_t)((c + 1) * 128 + wave * 32 + 16 + m) * 256;
#pragma unroll
      for (int ks = 0; ks < 4; ks++) {
        pb0[ks] = ld8(nBa + ks * 32 + k0);
        pb1[ks] = ld8(nBb + ks * 32 + k0);
      }
    }
    // LN2 fold + fast GELU (x * sigmoid(1.5957692(x + 0.044715x^3))) -> HC
#pragma unroll
    for (int nt = 0; nt < 2; nt++) {
      int col = wave * 32 + nt * 16 + m;
      int ch = c * 128 + col;
      float sg = sgb[ch], sb = sgb[1024 + ch], b1v = mb1[ch];
#pragma unroll
      for (int mt = 0; mt < 4; mt++)
#pragma unroll
        for (int rr = 0; rr < 4; rr++) {
          int tl = mt * 16 + gq * 4 + rr;
          float v = rsv[mt][rr] * acc1[mt][nt][rr] - rmuv[mt][rr] * sg + sb + b1v;
          float u = v * v;
          float y = v * __builtin_fmaf(0.07135481627f, u, 1.595769122f);
          float g = v / (1.f + __expf(-y));
          HC[tl * 136 + col] = f2b(g);
        }
    }
    __syncthreads();
    // mlp2 partial: K=128 (4 steps); wave owns 64 out-ch
#pragma unroll
    for (int ks = 0; ks < 4; ks++) {
      short8 a2[4];
#pragma unroll
      for (int mt = 0; mt < 4; mt++)
        a2[mt] = ld8(&HC[(mt * 16 + m) * 136 + ks * 32 + k0]);
      short8 bF[4];
#pragma unroll
      for (int nt = 0; nt < 4; nt++) {
        int ch = wave * 64 + nt * 16 + m;
        bF[nt] = ld8(W + WM2 + (size_t)ch * 1024 + c * 128 + ks * 32 + k0);
      }
#pragma unroll
      for (int mt = 0; mt < 4; mt++)
#pragma unroll
        for (int nt = 0; nt < 4; nt++)
          acc2[mt][nt] = mfma16(a2[mt], bF[nt], acc2[mt][nt]);
    }
    __syncthreads();  // before next chunk overwrites HC
  }
  // epilogue: + mb2 + residual (from XA), then NCHW out via ot halves
#pragma unroll
  for (int nt = 0; nt < 4; nt++) {
    int ch = wave * 64 + nt * 16 + m;
    float bias = mb2[ch];
#pragma unroll
    for (int mt = 0; mt < 4; mt++)
#pragma unroll
      for (int rr = 0; rr < 4; rr++) {
        int tl = mt * 16 + gq * 4 + rr;
        acc2[mt][nt][rr] += bias + b2f(XA[tl * 264 + ch]);
      }
  }
  __syncthreads();  // done with XA; reuse as ot
  float* ot = (float*)XA;  // [128][66] f32 = 33,792 B == sizeof(XA)
  int tg = tok0;
  int bimg = tg / 9216, hw0 = tg % 9216;
#pragma unroll
  for (int half = 0; half < 2; half++) {
    if ((wave >> 1) == half) {
#pragma unroll
      for (int nt = 0; nt < 4; nt++) {
        int jj = (wave & 1) * 64 + nt * 16 + m;  // 0..127 within half
#pragma unroll
        for (int mt = 0; mt < 4; mt++)
#pragma unroll
          for (int rr = 0; rr < 4; rr++) {
            int tl = mt * 16 + gq * 4 + rr;
            ot[jj * 66 + tl] = acc2[mt][nt][rr];
          }
      }
    }
    __syncthreads();
    for (int it = 0; it < 32; it++) {
      int flat = it * 256 + tid;
      int j = flat >> 6, t = flat & 63;
      out[((size_t)bimg * 256 + half * 128 + j) * 9216 + hw0 + t] = ot[j * 66 + t];
    }
    __syncthreads();
  }
}

extern "C" void kernel_launch(void* const* d_in, const int* in_sizes, int n_in,
                              void* d_out, int out_size, void* d_ws, size_t ws_size,
                              hipStream_t stream) {
  const float* x      = (const float*)d_in[0];
  const float* skipf  = (const float*)d_in[1];
  const float* up_w   = (const float*)d_in[2];
  const float* up_b   = (const float*)d_in[3];
  const float* skip_w = (const float*)d_in[4];
  const float* g1     = (const float*)d_in[5];
  const float* be1    = (const float*)d_in[6];
  const float* qkv_w  = (const float*)d_in[7];
  const float* qkv_b  = (const float*)d_in[8];
  const float* rpb    = (const float*)d_in[9];
  const float* proj_w = (const float*)d_in[10];
  const float* proj_b = (const float*)d_in[11];
  const float* g2     = (const float*)d_in[12];
  const float* be2    = (const float*)d_in[13];
  const float* m_w1   = (const float*)d_in[14];
  const float* m_b1   = (const float*)d_in[15];
  const float* m_w2   = (const float*)d_in[16];
  const float* m_b2   = (const float*)d_in[17];
  if (ws_size < WS_NEED) {
    k_sentinel<<<1, 256, 0, stream>>>((float*)d_out);
    return;
  }
  char* ws = (char*)d_ws;
  u16*   W    = (u16*)ws;
  float* bias = (float*)(ws + OFF_BIAS);
  u16*   sc   = (u16*)(ws + OFF_SC);
  u16*   xt   = (u16*)(ws + OFF_OVR);
  u16*   skt  = (u16*)(ws + OFF_OVR);
  float* stat = (float*)(ws + OFF_STAT);
  float* pst  = (float*)(ws + OFF_PST);
  float* sgb  = (float*)(ws + OFF_SGB);
  u16*   ybuf = (u16*)d_out;
  u16*   obr  = (u16*)((char*)d_out + 37748736u);

  k_prep<<<5504, 256, 0, stream>>>(qkv_w, proj_w, m_w1, m_w2, skip_w, up_w, rpb,
                                   g1, g2, W, bias);
  k_fold<<<704, 256, 0, stream>>>(m_w1, qkv_w, g1, be1, g2, be2, sgb);
  k_tr<<<dim3(72, 16, 8), 256, 0, stream>>>(x, xt, 512, 2304);
  k1g<<<dim3(144, 2, 4), 256, 0, stream>>>(W, xt, up_b, sc);
  k_tr_skip<<<dim3(3, 8, 768), 256, 0, stream>>>(skipf, skt);
  k2y<<<dim3(576, 2), 256, 0, stream>>>(W, skt, sc, ybuf, pst);
  k_statfin<<<288, 256, 0, stream>>>(pst, stat);
  k23<<<1568, 256, 0, stream>>>(W, ybuf, stat, sgb, qkv_b, bias, obr);
  k4r<<<dim3(576, 2), 256, 0, stream>>>(W, obr, proj_b, sc, pst);
  k_statfin<<<288, 256, 0, stream>>>(pst, stat);
  k56<<<1152, 256, 0, stream>>>(W, sc, stat, sgb, m_b1, m_b2, (float*)d_out);
}